// Round 15
// baseline (516.865 us; speedup 1.0000x reference)
//
#include <hip/hip_runtime.h>
#include <hip/hip_bf16.h>
#include <stdint.h>

// ---------------------------------------------------------------------------
// FMA-style hierarchical causal attention, MI355X (gfx950)
// B=4 T=8192 C=1024 H=16 D=64 M=64 P=8 L=6  -> BH=64, fine blocks nb0=128
// R15: (1) attn: V staged into its OWN LDS buffer, DMA issued BEFORE QK
//      (vmcnt(7) drains Q+K only; V covered by QK+softmax); post-QK alias
//      barrier deleted. (2) transposeV+poolV fused into vproc_k (one pass
//      over vb: vt + all 6 vtpool levels). GEMMs = R9 ring (frozen best).
// ---------------------------------------------------------------------------

typedef float  f32x4  __attribute__((ext_vector_type(4)));
typedef __bf16 bf16x8 __attribute__((ext_vector_type(8)));
typedef unsigned short ushort8 __attribute__((ext_vector_type(8)));
typedef unsigned short ushort4v __attribute__((ext_vector_type(4)));
typedef unsigned uint4v __attribute__((ext_vector_type(4)));

__device__ __forceinline__ unsigned short f2bf(float f) {
  union { float f; unsigned u; } v; v.f = f;
  unsigned r = v.u + 0x7fffu + ((v.u >> 16) & 1u);
  return (unsigned short)(r >> 16);
}
__device__ __forceinline__ float bf2f(unsigned short s) {
  union { unsigned u; float f; } v; v.u = ((unsigned)s) << 16;
  return v.f;
}
__device__ __forceinline__ bf16x8 ld_bf8(const unsigned short* p) {
  return __builtin_bit_cast(bf16x8, *(const ushort8*)p);
}
__device__ __forceinline__ f32x4 mfma16(bf16x8 a, bf16x8 b, f32x4 c) {
  return __builtin_amdgcn_mfma_f32_16x16x32_bf16(a, b, c, 0, 0, 0);
}
__device__ __forceinline__ f32x4 zero4() {
  f32x4 z; z[0] = 0.f; z[1] = 0.f; z[2] = 0.f; z[3] = 0.f; return z;
}
__device__ __forceinline__ void gload16(const void* g, void* lds) {
  __builtin_amdgcn_global_load_lds(
      (const __attribute__((address_space(1))) void*)(uintptr_t)g,
      (__attribute__((address_space(3))) void*)(unsigned int)(uintptr_t)lds,
      16, 0, 0);
}

#define T_SEQ 8192
#define NPOOL 2016   // 1024+512+256+128+64+32 pooled rows per bh

#define SCHED0() __builtin_amdgcn_sched_barrier(0)
#define VMC(n)                                           \
  do {                                                   \
    SCHED0();                                            \
    asm volatile("s_waitcnt vmcnt(" #n ")" ::: "memory");\
    SCHED0();                                            \
  } while (0)

// --------------------------- cast x -> bf16 --------------------------------
__global__ __launch_bounds__(256) void castx_k(const float* __restrict__ x,
                                               unsigned short* __restrict__ xb) {
  size_t i = ((size_t)blockIdx.x * 256 + threadIdx.x) * 8;
  float4 a = *(const float4*)(x + i);
  float4 b = *(const float4*)(x + i + 4);
  ushort8 o;
  o[0] = f2bf(a.x); o[1] = f2bf(a.y); o[2] = f2bf(a.z); o[3] = f2bf(a.w);
  o[4] = f2bf(b.x); o[5] = f2bf(b.y); o[6] = f2bf(b.z); o[7] = f2bf(b.w);
  *(ushort8*)(xb + i) = o;
}

// ---------------- transpose W [R][C] f32 -> [C][R] bf16 --------------------
__global__ __launch_bounds__(256) void transposeW_k(const float* __restrict__ w,
                                                    unsigned short* __restrict__ wt,
                                                    int R, int C) {
  __shared__ float tile[64 * 65];
  int cc = blockIdx.x, rc = blockIdx.y;
  int tid = threadIdx.x;
#pragma unroll
  for (int p = 0; p < 4; ++p) {
    int ci = p * 256 + tid;
    int r = ci >> 4, q4 = ci & 15;
    float4 v = *(const float4*)(w + (size_t)(rc * 64 + r) * C + cc * 64 + q4 * 4);
    tile[r * 65 + q4 * 4 + 0] = v.x;
    tile[r * 65 + q4 * 4 + 1] = v.y;
    tile[r * 65 + q4 * 4 + 2] = v.z;
    tile[r * 65 + q4 * 4 + 3] = v.w;
  }
  __syncthreads();
#pragma unroll
  for (int p = 0; p < 2; ++p) {
    int orow = p * 32 + (tid >> 3), tg = tid & 7;
    ushort8 ov;
#pragma unroll
    for (int i = 0; i < 8; ++i) ov[i] = f2bf(tile[(tg * 8 + i) * 65 + orow]);
    *(ushort8*)(wt + (size_t)(cc * 64 + orow) * R + rc * 64 + tg * 8) = ov;
  }
}

// ---------------------------------------------------------------------------
// 256x256 GEMM, K=1024, deepened K-half ring pipeline (R9, best measured).
// ---------------------------------------------------------------------------
template<int NTILE_N, int EPI>
__global__ __launch_bounds__(512, 2) void gemm256(
    const unsigned short* __restrict__ A, const unsigned short* __restrict__ Bt,
    const float* __restrict__ bias,
    unsigned short* __restrict__ o0, unsigned short* __restrict__ o1,
    unsigned short* __restrict__ o2, float* __restrict__ fout) {
  extern __shared__ __align__(16) char smem[];
  const int K = 1024;
  const int nwg = 128 * NTILE_N;
  const int q = nwg >> 3;
  const int wg = ((int)blockIdx.x & 7) * q + ((int)blockIdx.x >> 3);  // XCD swizzle
  const int tm = wg & 127, tn = wg >> 7;
  const int tid = threadIdx.x;
  const int wid = tid >> 6, lane = tid & 63;
  const int wm = wid >> 2, wn = wid & 3;
  const int lr = lane & 15, lg = lane >> 4;

  const int srow = tid >> 2;
  const int sseg = (tid & 3) ^ ((tid >> 3) & 3);
  const unsigned short* aSrc = A + (size_t)(tm * 256 + srow) * K + sseg * 8;
  const unsigned short* bSrc = Bt + (size_t)(tn * 256 + srow) * K + sseg * 8;
  const unsigned ldsT = (unsigned)tid * 16;

  const unsigned psel = (unsigned)((lg ^ ((lr >> 1) & 3)) * 16);
  const unsigned aBase = (unsigned)(wm * 8192 + lr * 64) + psel;
  const unsigned bBase = (unsigned)(16384 + wn * 4096 + lr * 64) + psel;

  f32x4 acc[8][4];
#pragma unroll
  for (int i = 0; i < 8; ++i)
#pragma unroll
    for (int j = 0; j < 4; ++j) acc[i][j] = zero4();

  bf16x8 rA0[4], rA1[4], rB0[4], rB1[4];

  auto SB = [&]() {
    SCHED0();
    __builtin_amdgcn_s_barrier();
    SCHED0();
  };
  auto stage2 = [&](int coffShorts, unsigned slotB) {
#pragma unroll
    for (int pass = 0; pass < 2; ++pass) {
      gload16(aSrc + (size_t)pass * 128 * K + coffShorts,
              smem + slotB + pass * 8192 + ldsT);
      gload16(bSrc + (size_t)pass * 128 * K + coffShorts,
              smem + slotB + 16384 + pass * 8192 + ldsT);
    }
  };
  auto rdA = [&](bf16x8 (&dst)[4], unsigned slotB, int ih) {
    const char* p = smem + slotB + aBase + ih * 4096;
#pragma unroll
    for (int ii = 0; ii < 4; ++ii)
      dst[ii] = ld_bf8((const unsigned short*)(p + ii * 1024));
  };
  auto rdB = [&](bf16x8 (&dst)[4], unsigned slotB) {
    const char* p = smem + slotB + bBase;
#pragma unroll
    for (int j = 0; j < 4; ++j)
      dst[j] = ld_bf8((const unsigned short*)(p + j * 1024));
  };
  auto cluster = [&](int rb, bf16x8 (&a)[4], bf16x8 (&b)[4]) {
    __builtin_amdgcn_s_setprio(1);
#pragma unroll
    for (int ii = 0; ii < 4; ++ii)
#pragma unroll
      for (int j = 0; j < 4; ++j)
        acc[rb + ii][j] = mfma16(b[j], a[ii], acc[rb + ii][j]);
    __builtin_amdgcn_s_setprio(0);
  };

  // prologue: stage tiles 0 and 1 (16 loads), certify t0
  stage2(0, 0u);
  stage2(32, 32768u);
  stage2(64, 65536u);
  stage2(96, 98304u);
  VMC(12);
  SB();
  rdA(rA0, 0u, 0);
  rdB(rB0, 0u);

  for (int t = 0; t < 16; ++t) {
    const unsigned s0  = (unsigned)((2 * t) & 3) * 32768u;
    const unsigned s1  = (unsigned)((2 * t + 1) & 3) * 32768u;
    const unsigned sn0 = (unsigned)((2 * t + 2) & 3) * 32768u;
    rdA(rA1, s0, 1);
    if (t < 15) { VMC(8); } else { VMC(0); }
    SB();
    cluster(0, rA0, rB0);
    if (t < 14) stage2((t + 2) * 64, s0);
    rdA(rA0, s1, 0);
    rdB(rB1, s1);
    SB();
    cluster(4, rA1, rB0);
    rdA(rA1, s1, 1);
    if (t < 14) { VMC(8); } else if (t == 14) { VMC(4); }
    SB();
    cluster(0, rA0, rB1);
    if (t < 14) stage2((t + 2) * 64 + 32, s1);
    if (t < 15) { rdA(rA0, sn0, 0); rdB(rB0, sn0); }
    SB();
    cluster(4, rA1, rB1);
  }

  const int mBase = tm * 256 + wm * 128;
  const int nBase = tn * 256 + wn * 64;
  if (EPI == 0) {
    const int region = nBase >> 10, nn = nBase & 1023, hh = nn >> 6;
    unsigned short* dst = region == 0 ? o0 : (region == 1 ? o1 : o2);
#pragma unroll
    for (int j = 0; j < 4; ++j) {
      const int d0 = (nn & 63) + j * 16 + lg * 4;
      const float4 bv = *(const float4*)(bias + nBase + j * 16 + lg * 4);
#pragma unroll
      for (int i = 0; i < 8; ++i) {
        const int m = mBase + i * 16 + lr;
        const int bb = m >> 13, tq = m & 8191;
        ushort4v pk;
        pk[0] = f2bf(acc[i][j][0] + bv.x);
        pk[1] = f2bf(acc[i][j][1] + bv.y);
        pk[2] = f2bf(acc[i][j][2] + bv.z);
        pk[3] = f2bf(acc[i][j][3] + bv.w);
        *(ushort4v*)(dst + (((size_t)(bb * 16 + hh)) * T_SEQ + tq) * 64 + d0) = pk;
      }
    }
  } else {
#pragma unroll
    for (int j = 0; j < 4; ++j) {
      const int n0 = nBase + j * 16 + lg * 4;
      const float4 bv = *(const float4*)(bias + n0);
#pragma unroll
      for (int i = 0; i < 8; ++i) {
        const int m = mBase + i * 16 + lr;
        float4 ov;
        ov.x = acc[i][j][0] + bv.x;
        ov.y = acc[i][j][1] + bv.y;
        ov.z = acc[i][j][2] + bv.z;
        ov.w = acc[i][j][3] + bv.w;
        *(float4*)(fout + (size_t)m * 1024 + n0) = ov;
      }
    }
  }
}

// ------ fused V pipeline: vb [bh][t][d] -> vt [bh][d][t] + vtpool ----------
// One block per (chunk of 256 t, bh). Transposes 4x 64x64 tiles to vt while
// accumulating level-1 (r=8) pool sums; then halves for levels 2..6.
__global__ __launch_bounds__(256) void vproc_k(const unsigned short* __restrict__ vb,
                                               unsigned short* __restrict__ vt,
                                               unsigned short* __restrict__ vtpool) {
  __shared__ float tile[64 * 65];
  __shared__ float pbuf[64 * 33];   // [d][32] level-1 means
  const int chunk = blockIdx.x;     // 0..31
  const int bh = blockIdx.y;
  const int tid = threadIdx.x;

#pragma unroll
  for (int s = 0; s < 4; ++s) {
    const int tbase = chunk * 256 + s * 64;
#pragma unroll
    for (int p = 0; p < 2; ++p) {
      int r = p * 32 + (tid >> 3), cg = tid & 7;
      ushort8 u = *(const ushort8*)(vb + ((size_t)bh * T_SEQ + tbase + r) * 64 + cg * 8);
#pragma unroll
      for (int i = 0; i < 8; ++i) tile[r * 65 + cg * 8 + i] = bf2f(u[i]);
    }
    __syncthreads();
#pragma unroll
    for (int p = 0; p < 2; ++p) {
      int dd = p * 32 + (tid >> 3), tg = tid & 7;
      ushort8 ov;
      float sum = 0.f;
#pragma unroll
      for (int i = 0; i < 8; ++i) {
        float v = tile[(tg * 8 + i) * 65 + dd];
        ov[i] = f2bf(v);
        sum += v;
      }
      *(ushort8*)(vt + ((size_t)bh * 64 + dd) * T_SEQ + tbase + tg * 8) = ov;
      pbuf[dd * 33 + s * 8 + tg] = sum * 0.125f;
    }
    __syncthreads();
  }

  unsigned short* vp = vtpool + ((size_t)bh * 64) * NPOOL;
  // level 1: 32 per d
  {
    const int d = tid >> 2, qq = tid & 3;
    ushort8 ov;
#pragma unroll
    for (int i = 0; i < 8; ++i) ov[i] = f2bf(pbuf[d * 33 + qq * 8 + i]);
    *(ushort8*)(vp + (size_t)d * NPOOL + chunk * 32 + qq * 8) = ov;
  }
  // level 2: 16 per d (also stash in tile[] scratch as [d][16])
  {
    const int d = tid >> 2, qq = tid & 3;
    ushort4v ov;
#pragma unroll
    for (int i = 0; i < 4; ++i) {
      const int j = qq * 4 + i;
      float v = 0.5f * (pbuf[d * 33 + 2 * j] + pbuf[d * 33 + 2 * j + 1]);
      tile[d * 17 + j] = v;
      ov[i] = f2bf(v);
    }
    *(ushort4v*)(vp + (size_t)d * NPOOL + 1024 + chunk * 16 + qq * 4) = ov;
  }
  __syncthreads();
  // levels 3..6 per-d (64 threads)
  if (tid < 64) {
    const int d = tid;
    float l3[8], l4[4], l5[2];
    ushort8 o3;
#pragma unroll
    for (int j = 0; j < 8; ++j) {
      l3[j] = 0.5f * (tile[d * 17 + 2 * j] + tile[d * 17 + 2 * j + 1]);
      o3[j] = f2bf(l3[j]);
    }
    *(ushort8*)(vp + (size_t)d * NPOOL + 1536 + chunk * 8) = o3;
    ushort4v o4;
#pragma unroll
    for (int j = 0; j < 4; ++j) {
      l4[j] = 0.5f * (l3[2 * j] + l3[2 * j + 1]);
      o4[j] = f2bf(l4[j]);
    }
    *(ushort4v*)(vp + (size_t)d * NPOOL + 1792 + chunk * 4) = o4;
#pragma unroll
    for (int j = 0; j < 2; ++j) {
      l5[j] = 0.5f * (l4[2 * j] + l4[2 * j + 1]);
      vp[(size_t)d * NPOOL + 1920 + chunk * 2 + j] = f2bf(l5[j]);
    }
    vp[(size_t)d * NPOOL + 1984 + chunk] = f2bf(0.5f * (l5[0] + l5[1]));
  }
}

// ---------------- pool K: k [bh][t][d] -> kpool [bh][2016][d] --------------
__global__ __launch_bounds__(256) void poolK_k(const unsigned short* __restrict__ kin,
                                               unsigned short* __restrict__ kpool) {
  __shared__ float buf[64 * 65];
  int chunk = blockIdx.x, bh = blockIdx.y;
  int tid = threadIdx.x;
  int cg = tid & 7, orow = tid >> 3;
  float s[8];
#pragma unroll
  for (int i = 0; i < 8; ++i) s[i] = 0.f;
  const unsigned short* base =
      kin + ((size_t)bh * T_SEQ + chunk * 256 + orow * 8) * 64 + cg * 8;
#pragma unroll
  for (int rr = 0; rr < 8; ++rr) {
    ushort8 v = *(const ushort8*)(base + (size_t)rr * 64);
#pragma unroll
    for (int i = 0; i < 8; ++i) s[i] += bf2f(v[i]);
  }
  unsigned short* kp = kpool + (size_t)bh * NPOOL * 64;
  {
    ushort8 ov;
#pragma unroll
    for (int i = 0; i < 8; ++i) {
      s[i] *= 0.125f;
      ov[i] = f2bf(s[i]);
      buf[orow * 65 + cg * 8 + i] = s[i];
    }
    *(ushort8*)(kp + ((size_t)(chunk * 32 + orow)) * 64 + cg * 8) = ov;
  }
  __syncthreads();
  int srcR = 0, dstR = 32;
#pragma unroll
  for (int lvl = 2; lvl <= 6; ++lvl) {
    int rows = 32 >> (lvl - 1);
    int off = 2048 - (2048 >> (lvl - 1));
    if (orow < rows) {
      ushort8 ov;
      float tv[8];
#pragma unroll
      for (int i = 0; i < 8; ++i) {
        tv[i] = 0.5f * (buf[(srcR + 2 * orow) * 65 + cg * 8 + i] +
                        buf[(srcR + 2 * orow + 1) * 65 + cg * 8 + i]);
        ov[i] = f2bf(tv[i]);
      }
      *(ushort8*)(kp + ((size_t)(off + chunk * rows + orow)) * 64 + cg * 8) = ov;
#pragma unroll
      for (int i = 0; i < 8; ++i) buf[(dstR + orow) * 65 + cg * 8 + i] = tv[i];
    }
    __syncthreads();
    srcR = dstR;
    dstR += rows;
  }
}

// ---------------- fused hierarchical attention (swapped QK^T) --------------
// K -> KV, V -> Vl (separate buffers), both DMA'd BEFORE QK. vmcnt(7)
// certifies Q+K; V drains at the pre-PV vmcnt(0) (covered by QK+softmax).
__global__ __launch_bounds__(256) void attn_k(const unsigned short* __restrict__ q,
                                              const unsigned short* __restrict__ k,
                                              const unsigned short* __restrict__ kpool,
                                              const unsigned short* __restrict__ vt,
                                              const unsigned short* __restrict__ vtpool,
                                              unsigned short* __restrict__ o) {
  const int bidx = (int)blockIdx.x;
  const int g = (bidx & 7) * 16 + (bidx >> 3);   // XCD-bucketed fine block
  const int bh = blockIdx.y;
  const int tid = threadIdx.x;
  const int w = tid >> 6, l = tid & 63;
  const int lr = l & 15, lg = l >> 4;
  __shared__ unsigned short KV[224 * 64];   // K-window
  __shared__ unsigned short Vl[224 * 64];   // V-window

  const size_t qoff = ((size_t)bh * T_SEQ + (size_t)g * 64 + w * 16 + lr) * 64 + lg * 8;
  bf16x8 aq0 = ld_bf8(q + qoff);
  bf16x8 aq1 = ld_bf8(q + qoff + 32);
  SCHED0();

  // ---- K-window staging: 7 passes x 32 rows; dest row*128 + seg*16 ----
  const int krow = tid >> 3;
  const int kseg = tid & 7;
#pragma unroll
  for (int p = 0; p < 7; ++p) {
    const int row = p * 32 + krow;
    const unsigned short* src;
    if (row < 128) {
      int t0 = (g - 1) * 64 + row;
      if (t0 < 0) t0 = 0;
      src = k + ((size_t)bh * T_SEQ + t0) * 64;
    } else {
      const int pr = row - 128;
      const int lvl0 = pr >> 4;
      const int off = 2048 - (2048 >> lvl0);
      const int gl = g >> lvl0;
      int st = (gl - 2) * 8 + (pr & 15);
      if (st < 0) st = 0;
      src = kpool + ((size_t)bh * NPOOL + off + st) * 64;
    }
    gload16(src + (kseg ^ (row & 7)) * 8,
            ((char*)KV) + p * 4096 + (unsigned)tid * 16);
  }
  SCHED0();

  // ---- V-window staging into Vl, issued BEFORE QK (stays in flight) ----
  const int vr = tid >> 2;
  const int vg = tid & 3;
  const int vswz = vg ^ ((vr >> 1) & 3);
#pragma unroll
  for (int s = 0; s < 7; ++s) {
    const int colsh = s * 32 + vswz * 8;
    const unsigned short* src;
    if (colsh < 128) {
      int t0 = (g - 1) * 64 + colsh;
      if (t0 < 0) t0 = 0;
      src = vt + ((size_t)bh * 64 + vr) * T_SEQ + t0;
    } else {
      const int c = colsh - 128;
      const int lvl = c >> 4;
      const int off = 2048 - (2048 >> lvl);
      const int gl = g >> lvl;
      int start = (gl - 2) * 8 + (c & 15);
      if (start < 0) start = 0;
      src = vtpool + ((size_t)bh * 64 + vr) * NPOOL + off + start;
    }
    gload16(src, ((char*)Vl) + s * 4096 + (unsigned)tid * 16);
  }
  SCHED0();
  asm volatile("s_waitcnt vmcnt(7)" ::: "memory");  // drains Q(2)+K(7); V in flight
  SCHED0();
  __builtin_amdgcn_s_barrier();                     // K staged for all waves
  SCHED0();

  // ---- QK^T from LDS, SWAPPED operands: A=K, B=Q ----
  f32x4 S[14];
#pragma unroll
  for (int ct = 0; ct < 14; ++ct) S[ct] = zero4();
#pragma unroll
  for (int ct = 0; ct < 14; ++ct) {
    const int row = ct * 16 + lr;
    const unsigned short* kr = KV + row * 64;
    const int sw = row & 7;
    S[ct] = mfma16(ld_bf8(kr + (lg ^ sw) * 8), aq0, S[ct]);
    S[ct] = mfma16(ld_bf8(kr + ((lg + 4) ^ sw) * 8), aq1, S[ct]);
  }
  SCHED0();

  // ---- mask + softmax: lane owns q = w*16+lr; k = ct*16 + lg*4 + e ----
  const float NEGF = -1e30f;
  const int qq = w * 16 + lr;
#pragma unroll
  for (int ct = 0; ct < 14; ++ct) {
#pragma unroll
    for (int e = 0; e < 4; ++e) {
      float s = S[ct][e] * 0.125f;
      bool valid;
      if (ct < 8) {
        int kk = ct * 16 + lg * 4 + e;
        valid = (kk > qq) && (kk <= qq + 64) && ((g >= 1) || (kk >= 64));
      } else {
        int lvl = ct - 7;
        int gl = g >> (lvl - 1);
        valid = gl >= ((lg < 2) ? 2 : 1);
      }
      S[ct][e] = valid ? s : NEGF;
    }
  }
  float mx = S[0][0];
#pragma unroll
  for (int ct = 0; ct < 14; ++ct)
#pragma unroll
    for (int e = 0; e < 4; ++e) mx = fmaxf(mx, S[ct][e]);
  mx = fmaxf(mx, __shfl_xor(mx, 16));
  mx = fmaxf(mx, __shfl_xor(mx, 32));
  float sum = 0.f;
#pragma unroll
  for (int ct = 0; ct < 14; ++ct) {
    const float sc = (ct < 8) ? 1.0f : (float)(8 << (ct - 8));
#pragma unroll
    for (int e = 0; e < 4; ++e) {
      float ev = sc * __expf(S[ct][e] - mx);
      S[ct][e] = ev;
      sum += ev;
    }
  }
  sum += __shfl_xor(sum, 16);
  sum += __shfl_xor(sum, 32);
  const float invd = 1.0f / sum;

  // ---- P -> bf16 words in registers ----
  unsigned pw[14][2];
#pragma unroll
  for (int ct = 0; ct < 14; ++ct) {
    float p0 = S[ct][0] * invd, p1 = S[ct][1] * invd;
    float p2 = S[ct][2] * invd, p3 = S[ct][3] * invd;
    asm("v_cvt_pk_bf16_f32 %0, %1, %2" : "=v"(pw[ct][0]) : "v"(p0), "v"(p1));
    asm("v_cvt_pk_bf16_f32 %0, %1, %2" : "=v"(pw[ct][1]) : "v"(p2), "v"(p3));
  }

  VMC(0);            // V DMA landed (per-wave)
  __syncthreads();   // V visible block-wide

  // ---- PV from LDS; A-fragment assembled per-kc ----
  const int src0 = lr + ((lg & 1) << 5);
  const int src1 = src0 + 16;
  const bool odd = (lg & 2) != 0;
  f32x4 O[4];
#pragma unroll
  for (int c2 = 0; c2 < 4; ++c2) O[c2] = zero4();
#pragma unroll
  for (int kc = 0; kc < 7; ++kc) {
    unsigned we0 = __shfl((int)pw[2 * kc][0], src0);
    unsigned we1 = __shfl((int)pw[2 * kc][1], src0);
    unsigned we2 = __shfl((int)pw[2 * kc][0], src1);
    unsigned we3 = __shfl((int)pw[2 * kc][1], src1);
    unsigned wo0 = __shfl((int)pw[2 * kc + 1][0], src0);
    unsigned wo1 = __shfl((int)pw[2 * kc + 1][1], src0);
    unsigned wo2 = __shfl((int)pw[2 * kc + 1][0], src1);
    unsigned wo3 = __shfl((int)pw[2 * kc + 1][1], src1);
    uint4v fw;
    fw[0] = odd ? wo0 : we0;
    fw[1] = odd ? wo1 : we1;
    fw[2] = odd ? wo2 : we2;
    fw[3] = odd ? wo3 : we3;
    bf16x8 paf = __builtin_bit_cast(bf16x8, fw);
#pragma unroll
    for (int c2 = 0; c2 < 4; ++c2) {
      const int row = c2 * 16 + lr;
      bf16x8 vb = ld_bf8(&Vl[kc * 2048 + row * 32 + ((lg ^ ((lr >> 1) & 3)) * 8)]);
      O[c2] = mfma16(paf, vb, O[c2]);
    }
  }
  const int bb = bh >> 4, hh = bh & 15;
#pragma unroll
  for (int c2 = 0; c2 < 4; ++c2) {
    int d = c2 * 16 + lr;
#pragma unroll
    for (int e = 0; e < 4; ++e) {
      int t = g * 64 + w * 16 + lg * 4 + e;
      o[((size_t)bb * T_SEQ + t) * 1024 + hh * 64 + d] = f2bf(O[c2][e]);
    }
  }
}

// ---------------------------------------------------------------------------
extern "C" void kernel_launch(void* const* d_in, const int* in_sizes, int n_in,
                              void* d_out, int out_size, void* d_ws, size_t ws_size,
                              hipStream_t stream) {
  const float* x  = (const float*)d_in[0];
  const float* Wa = (const float*)d_in[1];
  const float* ba = (const float*)d_in[2];
  const float* Wp = (const float*)d_in[3];
  const float* bp = (const float*)d_in[4];
  float* out = (float*)d_out;
  char* ws = (char*)d_ws;
  const size_t MB = 1024 * 1024;

  unsigned short* xb  = (unsigned short*)(ws);             // 64MB (dead after GEMM1)
  unsigned short* qb  = (unsigned short*)(ws + 64 * MB);   // 64MB
  unsigned short* kb  = (unsigned short*)(ws + 128 * MB);  // 64MB
  unsigned short* vb  = (unsigned short*)(ws + 192 * MB);  // 64MB (-> attn out)
  unsigned short* vt  = (unsigned short*)(ws + 256 * MB);  // 64MB
  unsigned short* wat = (unsigned short*)(ws + 320 * MB);  // 6MB
  unsigned short* wpt = (unsigned short*)(ws + 326 * MB);  // 2MB
  unsigned short* kpool  = xb;                             // aliases xb
  unsigned short* vtpool = (unsigned short*)(ws + 32 * MB);// aliases xb

  hipFuncSetAttribute((const void*)gemm256<12, 0>,
                      hipFuncAttributeMaxDynamicSharedMemorySize, 131072);
  hipFuncSetAttribute((const void*)gemm256<4, 1>,
                      hipFuncAttributeMaxDynamicSharedMemorySize, 131072);

  castx_k<<<16384, 256, 0, stream>>>(x, xb);
  transposeW_k<<<dim3(48, 16), 256, 0, stream>>>(Wa, wat, 1024, 3072);
  transposeW_k<<<dim3(16, 16), 256, 0, stream>>>(Wp, wpt, 1024, 1024);
  gemm256<12, 0><<<1536, 512, 131072, stream>>>(xb, wat, ba, qb, kb, vb, nullptr);
  vproc_k<<<dim3(32, 64), 256, 0, stream>>>(vb, vt, vtpool);
  poolK_k<<<dim3(32, 64), 256, 0, stream>>>(kb, kpool);
  attn_k<<<dim3(128, 64), 256, 0, stream>>>(qb, kb, kpool, vt, vtpool, vb);
  gemm256<4, 1><<<512, 512, 131072, stream>>>(vb, wpt, bp, nullptr, nullptr, nullptr, out);
}

// Round 16
// 508.657 us; speedup vs baseline: 1.0161x; 1.0161x over previous
//
#include <hip/hip_runtime.h>
#include <hip/hip_bf16.h>
#include <stdint.h>

// ---------------------------------------------------------------------------
// FMA-style hierarchical causal attention, MI355X (gfx950)
// B=4 T=8192 C=1024 H=16 D=64 M=64 P=8 L=6  -> BH=64, fine blocks nb0=128
// R16: R14's attn (single aliased KV buffer, V DMA post-QK, per-kc fragment
//      assembly) + R15's vproc_k fusion (transposeV+poolV in one pass).
//      GEMMs = R9 ring (frozen best).
// ---------------------------------------------------------------------------

typedef float  f32x4  __attribute__((ext_vector_type(4)));
typedef __bf16 bf16x8 __attribute__((ext_vector_type(8)));
typedef unsigned short ushort8 __attribute__((ext_vector_type(8)));
typedef unsigned short ushort4v __attribute__((ext_vector_type(4)));
typedef unsigned uint4v __attribute__((ext_vector_type(4)));

__device__ __forceinline__ unsigned short f2bf(float f) {
  union { float f; unsigned u; } v; v.f = f;
  unsigned r = v.u + 0x7fffu + ((v.u >> 16) & 1u);
  return (unsigned short)(r >> 16);
}
__device__ __forceinline__ float bf2f(unsigned short s) {
  union { unsigned u; float f; } v; v.u = ((unsigned)s) << 16;
  return v.f;
}
__device__ __forceinline__ bf16x8 ld_bf8(const unsigned short* p) {
  return __builtin_bit_cast(bf16x8, *(const ushort8*)p);
}
__device__ __forceinline__ f32x4 mfma16(bf16x8 a, bf16x8 b, f32x4 c) {
  return __builtin_amdgcn_mfma_f32_16x16x32_bf16(a, b, c, 0, 0, 0);
}
__device__ __forceinline__ f32x4 zero4() {
  f32x4 z; z[0] = 0.f; z[1] = 0.f; z[2] = 0.f; z[3] = 0.f; return z;
}
__device__ __forceinline__ void gload16(const void* g, void* lds) {
  __builtin_amdgcn_global_load_lds(
      (const __attribute__((address_space(1))) void*)(uintptr_t)g,
      (__attribute__((address_space(3))) void*)(unsigned int)(uintptr_t)lds,
      16, 0, 0);
}

#define T_SEQ 8192
#define NPOOL 2016   // 1024+512+256+128+64+32 pooled rows per bh

#define SCHED0() __builtin_amdgcn_sched_barrier(0)
#define VMC(n)                                           \
  do {                                                   \
    SCHED0();                                            \
    asm volatile("s_waitcnt vmcnt(" #n ")" ::: "memory");\
    SCHED0();                                            \
  } while (0)

// --------------------------- cast x -> bf16 --------------------------------
__global__ __launch_bounds__(256) void castx_k(const float* __restrict__ x,
                                               unsigned short* __restrict__ xb) {
  size_t i = ((size_t)blockIdx.x * 256 + threadIdx.x) * 8;
  float4 a = *(const float4*)(x + i);
  float4 b = *(const float4*)(x + i + 4);
  ushort8 o;
  o[0] = f2bf(a.x); o[1] = f2bf(a.y); o[2] = f2bf(a.z); o[3] = f2bf(a.w);
  o[4] = f2bf(b.x); o[5] = f2bf(b.y); o[6] = f2bf(b.z); o[7] = f2bf(b.w);
  *(ushort8*)(xb + i) = o;
}

// ---------------- transpose W [R][C] f32 -> [C][R] bf16 --------------------
__global__ __launch_bounds__(256) void transposeW_k(const float* __restrict__ w,
                                                    unsigned short* __restrict__ wt,
                                                    int R, int C) {
  __shared__ float tile[64 * 65];
  int cc = blockIdx.x, rc = blockIdx.y;
  int tid = threadIdx.x;
#pragma unroll
  for (int p = 0; p < 4; ++p) {
    int ci = p * 256 + tid;
    int r = ci >> 4, q4 = ci & 15;
    float4 v = *(const float4*)(w + (size_t)(rc * 64 + r) * C + cc * 64 + q4 * 4);
    tile[r * 65 + q4 * 4 + 0] = v.x;
    tile[r * 65 + q4 * 4 + 1] = v.y;
    tile[r * 65 + q4 * 4 + 2] = v.z;
    tile[r * 65 + q4 * 4 + 3] = v.w;
  }
  __syncthreads();
#pragma unroll
  for (int p = 0; p < 2; ++p) {
    int orow = p * 32 + (tid >> 3), tg = tid & 7;
    ushort8 ov;
#pragma unroll
    for (int i = 0; i < 8; ++i) ov[i] = f2bf(tile[(tg * 8 + i) * 65 + orow]);
    *(ushort8*)(wt + (size_t)(cc * 64 + orow) * R + rc * 64 + tg * 8) = ov;
  }
}

// ---------------------------------------------------------------------------
// 256x256 GEMM, K=1024, deepened K-half ring pipeline (R9, best measured).
// ---------------------------------------------------------------------------
template<int NTILE_N, int EPI>
__global__ __launch_bounds__(512, 2) void gemm256(
    const unsigned short* __restrict__ A, const unsigned short* __restrict__ Bt,
    const float* __restrict__ bias,
    unsigned short* __restrict__ o0, unsigned short* __restrict__ o1,
    unsigned short* __restrict__ o2, float* __restrict__ fout) {
  extern __shared__ __align__(16) char smem[];
  const int K = 1024;
  const int nwg = 128 * NTILE_N;
  const int q = nwg >> 3;
  const int wg = ((int)blockIdx.x & 7) * q + ((int)blockIdx.x >> 3);  // XCD swizzle
  const int tm = wg & 127, tn = wg >> 7;
  const int tid = threadIdx.x;
  const int wid = tid >> 6, lane = tid & 63;
  const int wm = wid >> 2, wn = wid & 3;
  const int lr = lane & 15, lg = lane >> 4;

  const int srow = tid >> 2;
  const int sseg = (tid & 3) ^ ((tid >> 3) & 3);
  const unsigned short* aSrc = A + (size_t)(tm * 256 + srow) * K + sseg * 8;
  const unsigned short* bSrc = Bt + (size_t)(tn * 256 + srow) * K + sseg * 8;
  const unsigned ldsT = (unsigned)tid * 16;

  const unsigned psel = (unsigned)((lg ^ ((lr >> 1) & 3)) * 16);
  const unsigned aBase = (unsigned)(wm * 8192 + lr * 64) + psel;
  const unsigned bBase = (unsigned)(16384 + wn * 4096 + lr * 64) + psel;

  f32x4 acc[8][4];
#pragma unroll
  for (int i = 0; i < 8; ++i)
#pragma unroll
    for (int j = 0; j < 4; ++j) acc[i][j] = zero4();

  bf16x8 rA0[4], rA1[4], rB0[4], rB1[4];

  auto SB = [&]() {
    SCHED0();
    __builtin_amdgcn_s_barrier();
    SCHED0();
  };
  auto stage2 = [&](int coffShorts, unsigned slotB) {
#pragma unroll
    for (int pass = 0; pass < 2; ++pass) {
      gload16(aSrc + (size_t)pass * 128 * K + coffShorts,
              smem + slotB + pass * 8192 + ldsT);
      gload16(bSrc + (size_t)pass * 128 * K + coffShorts,
              smem + slotB + 16384 + pass * 8192 + ldsT);
    }
  };
  auto rdA = [&](bf16x8 (&dst)[4], unsigned slotB, int ih) {
    const char* p = smem + slotB + aBase + ih * 4096;
#pragma unroll
    for (int ii = 0; ii < 4; ++ii)
      dst[ii] = ld_bf8((const unsigned short*)(p + ii * 1024));
  };
  auto rdB = [&](bf16x8 (&dst)[4], unsigned slotB) {
    const char* p = smem + slotB + bBase;
#pragma unroll
    for (int j = 0; j < 4; ++j)
      dst[j] = ld_bf8((const unsigned short*)(p + j * 1024));
  };
  auto cluster = [&](int rb, bf16x8 (&a)[4], bf16x8 (&b)[4]) {
    __builtin_amdgcn_s_setprio(1);
#pragma unroll
    for (int ii = 0; ii < 4; ++ii)
#pragma unroll
      for (int j = 0; j < 4; ++j)
        acc[rb + ii][j] = mfma16(b[j], a[ii], acc[rb + ii][j]);
    __builtin_amdgcn_s_setprio(0);
  };

  // prologue: stage tiles 0 and 1 (16 loads), certify t0
  stage2(0, 0u);
  stage2(32, 32768u);
  stage2(64, 65536u);
  stage2(96, 98304u);
  VMC(12);
  SB();
  rdA(rA0, 0u, 0);
  rdB(rB0, 0u);

  for (int t = 0; t < 16; ++t) {
    const unsigned s0  = (unsigned)((2 * t) & 3) * 32768u;
    const unsigned s1  = (unsigned)((2 * t + 1) & 3) * 32768u;
    const unsigned sn0 = (unsigned)((2 * t + 2) & 3) * 32768u;
    rdA(rA1, s0, 1);
    if (t < 15) { VMC(8); } else { VMC(0); }
    SB();
    cluster(0, rA0, rB0);
    if (t < 14) stage2((t + 2) * 64, s0);
    rdA(rA0, s1, 0);
    rdB(rB1, s1);
    SB();
    cluster(4, rA1, rB0);
    rdA(rA1, s1, 1);
    if (t < 14) { VMC(8); } else if (t == 14) { VMC(4); }
    SB();
    cluster(0, rA0, rB1);
    if (t < 14) stage2((t + 2) * 64 + 32, s1);
    if (t < 15) { rdA(rA0, sn0, 0); rdB(rB0, sn0); }
    SB();
    cluster(4, rA1, rB1);
  }

  const int mBase = tm * 256 + wm * 128;
  const int nBase = tn * 256 + wn * 64;
  if (EPI == 0) {
    const int region = nBase >> 10, nn = nBase & 1023, hh = nn >> 6;
    unsigned short* dst = region == 0 ? o0 : (region == 1 ? o1 : o2);
#pragma unroll
    for (int j = 0; j < 4; ++j) {
      const int d0 = (nn & 63) + j * 16 + lg * 4;
      const float4 bv = *(const float4*)(bias + nBase + j * 16 + lg * 4);
#pragma unroll
      for (int i = 0; i < 8; ++i) {
        const int m = mBase + i * 16 + lr;
        const int bb = m >> 13, tq = m & 8191;
        ushort4v pk;
        pk[0] = f2bf(acc[i][j][0] + bv.x);
        pk[1] = f2bf(acc[i][j][1] + bv.y);
        pk[2] = f2bf(acc[i][j][2] + bv.z);
        pk[3] = f2bf(acc[i][j][3] + bv.w);
        *(ushort4v*)(dst + (((size_t)(bb * 16 + hh)) * T_SEQ + tq) * 64 + d0) = pk;
      }
    }
  } else {
#pragma unroll
    for (int j = 0; j < 4; ++j) {
      const int n0 = nBase + j * 16 + lg * 4;
      const float4 bv = *(const float4*)(bias + n0);
#pragma unroll
      for (int i = 0; i < 8; ++i) {
        const int m = mBase + i * 16 + lr;
        float4 ov;
        ov.x = acc[i][j][0] + bv.x;
        ov.y = acc[i][j][1] + bv.y;
        ov.z = acc[i][j][2] + bv.z;
        ov.w = acc[i][j][3] + bv.w;
        *(float4*)(fout + (size_t)m * 1024 + n0) = ov;
      }
    }
  }
}

// ------ fused V pipeline: vb [bh][t][d] -> vt [bh][d][t] + vtpool ----------
// One block per (chunk of 256 t, bh). Transposes 4x 64x64 tiles to vt while
// accumulating level-1 (r=8) pool means; then halves for levels 2..6.
__global__ __launch_bounds__(256) void vproc_k(const unsigned short* __restrict__ vb,
                                               unsigned short* __restrict__ vt,
                                               unsigned short* __restrict__ vtpool) {
  __shared__ float tile[64 * 65];
  __shared__ float pbuf[64 * 33];   // [d][32] level-1 means
  const int chunk = blockIdx.x;     // 0..31
  const int bh = blockIdx.y;
  const int tid = threadIdx.x;

#pragma unroll
  for (int s = 0; s < 4; ++s) {
    const int tbase = chunk * 256 + s * 64;
#pragma unroll
    for (int p = 0; p < 2; ++p) {
      int r = p * 32 + (tid >> 3), cg = tid & 7;
      ushort8 u = *(const ushort8*)(vb + ((size_t)bh * T_SEQ + tbase + r) * 64 + cg * 8);
#pragma unroll
      for (int i = 0; i < 8; ++i) tile[r * 65 + cg * 8 + i] = bf2f(u[i]);
    }
    __syncthreads();
#pragma unroll
    for (int p = 0; p < 2; ++p) {
      int dd = p * 32 + (tid >> 3), tg = tid & 7;
      ushort8 ov;
      float sum = 0.f;
#pragma unroll
      for (int i = 0; i < 8; ++i) {
        float v = tile[(tg * 8 + i) * 65 + dd];
        ov[i] = f2bf(v);
        sum += v;
      }
      *(ushort8*)(vt + ((size_t)bh * 64 + dd) * T_SEQ + tbase + tg * 8) = ov;
      pbuf[dd * 33 + s * 8 + tg] = sum * 0.125f;
    }
    __syncthreads();
  }

  unsigned short* vp = vtpool + ((size_t)bh * 64) * NPOOL;
  // level 1: 32 per d
  {
    const int d = tid >> 2, qq = tid & 3;
    ushort8 ov;
#pragma unroll
    for (int i = 0; i < 8; ++i) ov[i] = f2bf(pbuf[d * 33 + qq * 8 + i]);
    *(ushort8*)(vp + (size_t)d * NPOOL + chunk * 32 + qq * 8) = ov;
  }
  // level 2: 16 per d (stash in tile[] scratch as [d][16])
  {
    const int d = tid >> 2, qq = tid & 3;
    ushort4v ov;
#pragma unroll
    for (int i = 0; i < 4; ++i) {
      const int j = qq * 4 + i;
      float v = 0.5f * (pbuf[d * 33 + 2 * j] + pbuf[d * 33 + 2 * j + 1]);
      tile[d * 17 + j] = v;
      ov[i] = f2bf(v);
    }
    *(ushort4v*)(vp + (size_t)d * NPOOL + 1024 + chunk * 16 + qq * 4) = ov;
  }
  __syncthreads();
  // levels 3..6 per-d (64 threads)
  if (tid < 64) {
    const int d = tid;
    float l3[8], l4[4], l5[2];
    ushort8 o3;
#pragma unroll
    for (int j = 0; j < 8; ++j) {
      l3[j] = 0.5f * (tile[d * 17 + 2 * j] + tile[d * 17 + 2 * j + 1]);
      o3[j] = f2bf(l3[j]);
    }
    *(ushort8*)(vp + (size_t)d * NPOOL + 1536 + chunk * 8) = o3;
    ushort4v o4;
#pragma unroll
    for (int j = 0; j < 4; ++j) {
      l4[j] = 0.5f * (l3[2 * j] + l3[2 * j + 1]);
      o4[j] = f2bf(l4[j]);
    }
    *(ushort4v*)(vp + (size_t)d * NPOOL + 1792 + chunk * 4) = o4;
#pragma unroll
    for (int j = 0; j < 2; ++j) {
      l5[j] = 0.5f * (l4[2 * j] + l4[2 * j + 1]);
      vp[(size_t)d * NPOOL + 1920 + chunk * 2 + j] = f2bf(l5[j]);
    }
    vp[(size_t)d * NPOOL + 1984 + chunk] = f2bf(0.5f * (l5[0] + l5[1]));
  }
}

// ---------------- pool K: k [bh][t][d] -> kpool [bh][2016][d] --------------
__global__ __launch_bounds__(256) void poolK_k(const unsigned short* __restrict__ kin,
                                               unsigned short* __restrict__ kpool) {
  __shared__ float buf[64 * 65];
  int chunk = blockIdx.x, bh = blockIdx.y;
  int tid = threadIdx.x;
  int cg = tid & 7, orow = tid >> 3;
  float s[8];
#pragma unroll
  for (int i = 0; i < 8; ++i) s[i] = 0.f;
  const unsigned short* base =
      kin + ((size_t)bh * T_SEQ + chunk * 256 + orow * 8) * 64 + cg * 8;
#pragma unroll
  for (int rr = 0; rr < 8; ++rr) {
    ushort8 v = *(const ushort8*)(base + (size_t)rr * 64);
#pragma unroll
    for (int i = 0; i < 8; ++i) s[i] += bf2f(v[i]);
  }
  unsigned short* kp = kpool + (size_t)bh * NPOOL * 64;
  {
    ushort8 ov;
#pragma unroll
    for (int i = 0; i < 8; ++i) {
      s[i] *= 0.125f;
      ov[i] = f2bf(s[i]);
      buf[orow * 65 + cg * 8 + i] = s[i];
    }
    *(ushort8*)(kp + ((size_t)(chunk * 32 + orow)) * 64 + cg * 8) = ov;
  }
  __syncthreads();
  int srcR = 0, dstR = 32;
#pragma unroll
  for (int lvl = 2; lvl <= 6; ++lvl) {
    int rows = 32 >> (lvl - 1);
    int off = 2048 - (2048 >> (lvl - 1));
    if (orow < rows) {
      ushort8 ov;
      float tv[8];
#pragma unroll
      for (int i = 0; i < 8; ++i) {
        tv[i] = 0.5f * (buf[(srcR + 2 * orow) * 65 + cg * 8 + i] +
                        buf[(srcR + 2 * orow + 1) * 65 + cg * 8 + i]);
        ov[i] = f2bf(tv[i]);
      }
      *(ushort8*)(kp + ((size_t)(off + chunk * rows + orow)) * 64 + cg * 8) = ov;
#pragma unroll
      for (int i = 0; i < 8; ++i) buf[(dstR + orow) * 65 + cg * 8 + i] = tv[i];
    }
    __syncthreads();
    srcR = dstR;
    dstR += rows;
  }
}

// ---------------- fused hierarchical attention (swapped QK^T) --------------
// R14 structure: single aliased KV buffer; K DMA'd pre-QK; V DMA'd after the
// post-QK barrier into the same space; per-kc PV fragment assembly.
__global__ __launch_bounds__(256, 4) void attn_k(const unsigned short* __restrict__ q,
                                                 const unsigned short* __restrict__ k,
                                                 const unsigned short* __restrict__ kpool,
                                                 const unsigned short* __restrict__ vt,
                                                 const unsigned short* __restrict__ vtpool,
                                                 unsigned short* __restrict__ o) {
  const int bidx = (int)blockIdx.x;
  const int g = (bidx & 7) * 16 + (bidx >> 3);   // XCD-bucketed fine block
  const int bh = blockIdx.y;
  const int tid = threadIdx.x;
  const int w = tid >> 6, l = tid & 63;
  const int lr = l & 15, lg = l >> 4;
  __shared__ unsigned short KV[224 * 64];   // 28672B: K-window, then V-window

  const size_t qoff = ((size_t)bh * T_SEQ + (size_t)g * 64 + w * 16 + lr) * 64 + lg * 8;
  bf16x8 aq0 = ld_bf8(q + qoff);
  bf16x8 aq1 = ld_bf8(q + qoff + 32);
  SCHED0();

  // ---- K-window staging: 7 passes x 32 rows; dest row*128 + seg*16 ----
  const int krow = tid >> 3;
  const int kseg = tid & 7;
#pragma unroll
  for (int p = 0; p < 7; ++p) {
    const int row = p * 32 + krow;
    const unsigned short* src;
    if (row < 128) {
      int t0 = (g - 1) * 64 + row;
      if (t0 < 0) t0 = 0;
      src = k + ((size_t)bh * T_SEQ + t0) * 64;
    } else {
      const int pr = row - 128;
      const int lvl0 = pr >> 4;
      const int off = 2048 - (2048 >> lvl0);
      const int gl = g >> lvl0;
      int st = (gl - 2) * 8 + (pr & 15);
      if (st < 0) st = 0;
      src = kpool + ((size_t)bh * NPOOL + off + st) * 64;
    }
    gload16(src + (kseg ^ (row & 7)) * 8,
            ((char*)KV) + p * 4096 + (unsigned)tid * 16);
  }
  VMC(0);                          // Q + K drained
  __builtin_amdgcn_s_barrier();    // K staged for all waves
  SCHED0();

  // ---- QK^T from LDS, SWAPPED operands: A=K, B=Q ----
  f32x4 S[14];
#pragma unroll
  for (int ct = 0; ct < 14; ++ct) S[ct] = zero4();
#pragma unroll
  for (int ct = 0; ct < 14; ++ct) {
    const int row = ct * 16 + lr;
    const unsigned short* kr = KV + row * 64;
    const int sw = row & 7;
    S[ct] = mfma16(ld_bf8(kr + (lg ^ sw) * 8), aq0, S[ct]);
    S[ct] = mfma16(ld_bf8(kr + ((lg + 4) ^ sw) * 8), aq1, S[ct]);
  }
  SCHED0();
  __builtin_amdgcn_s_barrier();    // all waves done reading K from KV
  SCHED0();

  // ---- V-window staging into the aliased LDS (DMA lands under softmax) ---
  const int vr = tid >> 2;
  const int vg = tid & 3;
  const int vswz = vg ^ ((vr >> 1) & 3);
#pragma unroll
  for (int s = 0; s < 7; ++s) {
    const int colsh = s * 32 + vswz * 8;
    const unsigned short* src;
    if (colsh < 128) {
      int t0 = (g - 1) * 64 + colsh;
      if (t0 < 0) t0 = 0;
      src = vt + ((size_t)bh * 64 + vr) * T_SEQ + t0;
    } else {
      const int c = colsh - 128;
      const int lvl = c >> 4;
      const int off = 2048 - (2048 >> lvl);
      const int gl = g >> lvl;
      int start = (gl - 2) * 8 + (c & 15);
      if (start < 0) start = 0;
      src = vtpool + ((size_t)bh * 64 + vr) * NPOOL + off + start;
    }
    gload16(src, ((char*)KV) + s * 4096 + (unsigned)tid * 16);
  }
  SCHED0();

  // ---- mask + softmax: lane owns q = w*16+lr; k = ct*16 + lg*4 + e ----
  const float NEGF = -1e30f;
  const int qq = w * 16 + lr;
#pragma unroll
  for (int ct = 0; ct < 14; ++ct) {
#pragma unroll
    for (int e = 0; e < 4; ++e) {
      float s = S[ct][e] * 0.125f;
      bool valid;
      if (ct < 8) {
        int kk = ct * 16 + lg * 4 + e;
        valid = (kk > qq) && (kk <= qq + 64) && ((g >= 1) || (kk >= 64));
      } else {
        int lvl = ct - 7;
        int gl = g >> (lvl - 1);
        valid = gl >= ((lg < 2) ? 2 : 1);
      }
      S[ct][e] = valid ? s : NEGF;
    }
  }
  float mx = S[0][0];
#pragma unroll
  for (int ct = 0; ct < 14; ++ct)
#pragma unroll
    for (int e = 0; e < 4; ++e) mx = fmaxf(mx, S[ct][e]);
  mx = fmaxf(mx, __shfl_xor(mx, 16));
  mx = fmaxf(mx, __shfl_xor(mx, 32));
  float sum = 0.f;
#pragma unroll
  for (int ct = 0; ct < 14; ++ct) {
    const float sc = (ct < 8) ? 1.0f : (float)(8 << (ct - 8));
#pragma unroll
    for (int e = 0; e < 4; ++e) {
      float ev = sc * __expf(S[ct][e] - mx);
      S[ct][e] = ev;
      sum += ev;
    }
  }
  sum += __shfl_xor(sum, 16);
  sum += __shfl_xor(sum, 32);
  const float invd = 1.0f / sum;

  // ---- P -> bf16 words in registers (S dies here) ----
  unsigned pw[14][2];
#pragma unroll
  for (int ct = 0; ct < 14; ++ct) {
    float p0 = S[ct][0] * invd, p1 = S[ct][1] * invd;
    float p2 = S[ct][2] * invd, p3 = S[ct][3] * invd;
    asm("v_cvt_pk_bf16_f32 %0, %1, %2" : "=v"(pw[ct][0]) : "v"(p0), "v"(p1));
    asm("v_cvt_pk_bf16_f32 %0, %1, %2" : "=v"(pw[ct][1]) : "v"(p2), "v"(p3));
  }

  VMC(0);            // V DMA landed (per-wave)
  __syncthreads();   // V visible block-wide

  // ---- PV from LDS; A-fragment assembled per-kc (1 live fragment) ----
  const int src0 = lr + ((lg & 1) << 5);
  const int src1 = src0 + 16;
  const bool odd = (lg & 2) != 0;
  f32x4 O[4];
#pragma unroll
  for (int c2 = 0; c2 < 4; ++c2) O[c2] = zero4();
#pragma unroll
  for (int kc = 0; kc < 7; ++kc) {
    unsigned we0 = __shfl((int)pw[2 * kc][0], src0);
    unsigned we1 = __shfl((int)pw[2 * kc][1], src0);
    unsigned we2 = __shfl((int)pw[2 * kc][0], src1);
    unsigned we3 = __shfl((int)pw[2 * kc][1], src1);
    unsigned wo0 = __shfl((int)pw[2 * kc + 1][0], src0);
    unsigned wo1 = __shfl((int)pw[2 * kc + 1][1], src0);
    unsigned wo2 = __shfl((int)pw[2 * kc + 1][0], src1);
    unsigned wo3 = __shfl((int)pw[2 * kc + 1][1], src1);
    uint4v fw;
    fw[0] = odd ? wo0 : we0;
    fw[1] = odd ? wo1 : we1;
    fw[2] = odd ? wo2 : we2;
    fw[3] = odd ? wo3 : we3;
    bf16x8 paf = __builtin_bit_cast(bf16x8, fw);
#pragma unroll
    for (int c2 = 0; c2 < 4; ++c2) {
      const int row = c2 * 16 + lr;
      bf16x8 vb = ld_bf8(&KV[kc * 2048 + row * 32 + ((lg ^ ((lr >> 1) & 3)) * 8)]);
      O[c2] = mfma16(paf, vb, O[c2]);
    }
  }
  const int bb = bh >> 4, hh = bh & 15;
#pragma unroll
  for (int c2 = 0; c2 < 4; ++c2) {
    int d = c2 * 16 + lr;
#pragma unroll
    for (int e = 0; e < 4; ++e) {
      int t = g * 64 + w * 16 + lg * 4 + e;
      o[((size_t)bb * T_SEQ + t) * 1024 + hh * 64 + d] = f2bf(O[c2][e]);
    }
  }
}

// ---------------------------------------------------------------------------
extern "C" void kernel_launch(void* const* d_in, const int* in_sizes, int n_in,
                              void* d_out, int out_size, void* d_ws, size_t ws_size,
                              hipStream_t stream) {
  const float* x  = (const float*)d_in[0];
  const float* Wa = (const float*)d_in[1];
  const float* ba = (const float*)d_in[2];
  const float* Wp = (const float*)d_in[3];
  const float* bp = (const float*)d_in[4];
  float* out = (float*)d_out;
  char* ws = (char*)d_ws;
  const size_t MB = 1024 * 1024;

  unsigned short* xb  = (unsigned short*)(ws);             // 64MB (dead after GEMM1)
  unsigned short* qb  = (unsigned short*)(ws + 64 * MB);   // 64MB
  unsigned short* kb  = (unsigned short*)(ws + 128 * MB);  // 64MB
  unsigned short* vb  = (unsigned short*)(ws + 192 * MB);  // 64MB (-> attn out)
  unsigned short* vt  = (unsigned short*)(ws + 256 * MB);  // 64MB
  unsigned short* wat = (unsigned short*)(ws + 320 * MB);  // 6MB
  unsigned short* wpt = (unsigned short*)(ws + 326 * MB);  // 2MB
  unsigned short* kpool  = xb;                             // aliases xb
  unsigned short* vtpool = (unsigned short*)(ws + 32 * MB);// aliases xb

  hipFuncSetAttribute((const void*)gemm256<12, 0>,
                      hipFuncAttributeMaxDynamicSharedMemorySize, 131072);
  hipFuncSetAttribute((const void*)gemm256<4, 1>,
                      hipFuncAttributeMaxDynamicSharedMemorySize, 131072);

  castx_k<<<16384, 256, 0, stream>>>(x, xb);
  transposeW_k<<<dim3(48, 16), 256, 0, stream>>>(Wa, wat, 1024, 3072);
  transposeW_k<<<dim3(16, 16), 256, 0, stream>>>(Wp, wpt, 1024, 1024);
  gemm256<12, 0><<<1536, 512, 131072, stream>>>(xb, wat, ba, qb, kb, vb, nullptr);
  vproc_k<<<dim3(32, 64), 256, 0, stream>>>(vb, vt, vtpool);
  poolK_k<<<dim3(32, 64), 256, 0, stream>>>(kb, kpool);
  attn_k<<<dim3(128, 64), 256, 0, stream>>>(qb, kb, kpool, vt, vtpool, vb);
  gemm256<4, 1><<<512, 512, 131072, stream>>>(vb, wpt, bp, nullptr, nullptr, nullptr, out);
}

// Round 17
// 497.332 us; speedup vs baseline: 1.0393x; 1.0228x over previous
//
#include <hip/hip_runtime.h>
#include <hip/hip_bf16.h>
#include <stdint.h>

// ---------------------------------------------------------------------------
// FMA-style hierarchical causal attention, MI355X (gfx950)
// B=4 T=8192 C=1024 H=16 D=64 M=64 P=8 L=6  -> BH=64, fine blocks nb0=128
// R17: revert to R14 exactly (best measured, 497.7us). GEMM = R9 ring;
//      attn = swapped QK^T, in-register P, aliased KV, XCD-bucketed grid;
//      separate transposeV / poolK / poolV (vproc fusion measured-negative).
// ---------------------------------------------------------------------------

typedef float  f32x4  __attribute__((ext_vector_type(4)));
typedef __bf16 bf16x8 __attribute__((ext_vector_type(8)));
typedef unsigned short ushort8 __attribute__((ext_vector_type(8)));
typedef unsigned short ushort4v __attribute__((ext_vector_type(4)));
typedef unsigned uint4v __attribute__((ext_vector_type(4)));

__device__ __forceinline__ unsigned short f2bf(float f) {
  union { float f; unsigned u; } v; v.f = f;
  unsigned r = v.u + 0x7fffu + ((v.u >> 16) & 1u);
  return (unsigned short)(r >> 16);
}
__device__ __forceinline__ float bf2f(unsigned short s) {
  union { unsigned u; float f; } v; v.u = ((unsigned)s) << 16;
  return v.f;
}
__device__ __forceinline__ bf16x8 ld_bf8(const unsigned short* p) {
  return __builtin_bit_cast(bf16x8, *(const ushort8*)p);
}
__device__ __forceinline__ f32x4 mfma16(bf16x8 a, bf16x8 b, f32x4 c) {
  return __builtin_amdgcn_mfma_f32_16x16x32_bf16(a, b, c, 0, 0, 0);
}
__device__ __forceinline__ f32x4 zero4() {
  f32x4 z; z[0] = 0.f; z[1] = 0.f; z[2] = 0.f; z[3] = 0.f; return z;
}
__device__ __forceinline__ void gload16(const void* g, void* lds) {
  __builtin_amdgcn_global_load_lds(
      (const __attribute__((address_space(1))) void*)(uintptr_t)g,
      (__attribute__((address_space(3))) void*)(unsigned int)(uintptr_t)lds,
      16, 0, 0);
}

#define T_SEQ 8192
#define NPOOL 2016   // 1024+512+256+128+64+32 pooled rows per bh

#define SCHED0() __builtin_amdgcn_sched_barrier(0)
#define VMC(n)                                           \
  do {                                                   \
    SCHED0();                                            \
    asm volatile("s_waitcnt vmcnt(" #n ")" ::: "memory");\
    SCHED0();                                            \
  } while (0)

// --------------------------- cast x -> bf16 --------------------------------
__global__ __launch_bounds__(256) void castx_k(const float* __restrict__ x,
                                               unsigned short* __restrict__ xb) {
  size_t i = ((size_t)blockIdx.x * 256 + threadIdx.x) * 8;
  float4 a = *(const float4*)(x + i);
  float4 b = *(const float4*)(x + i + 4);
  ushort8 o;
  o[0] = f2bf(a.x); o[1] = f2bf(a.y); o[2] = f2bf(a.z); o[3] = f2bf(a.w);
  o[4] = f2bf(b.x); o[5] = f2bf(b.y); o[6] = f2bf(b.z); o[7] = f2bf(b.w);
  *(ushort8*)(xb + i) = o;
}

// ---------------- transpose W [R][C] f32 -> [C][R] bf16 --------------------
__global__ __launch_bounds__(256) void transposeW_k(const float* __restrict__ w,
                                                    unsigned short* __restrict__ wt,
                                                    int R, int C) {
  __shared__ float tile[64 * 65];
  int cc = blockIdx.x, rc = blockIdx.y;
  int tid = threadIdx.x;
#pragma unroll
  for (int p = 0; p < 4; ++p) {
    int ci = p * 256 + tid;
    int r = ci >> 4, q4 = ci & 15;
    float4 v = *(const float4*)(w + (size_t)(rc * 64 + r) * C + cc * 64 + q4 * 4);
    tile[r * 65 + q4 * 4 + 0] = v.x;
    tile[r * 65 + q4 * 4 + 1] = v.y;
    tile[r * 65 + q4 * 4 + 2] = v.z;
    tile[r * 65 + q4 * 4 + 3] = v.w;
  }
  __syncthreads();
#pragma unroll
  for (int p = 0; p < 2; ++p) {
    int orow = p * 32 + (tid >> 3), tg = tid & 7;
    ushort8 ov;
#pragma unroll
    for (int i = 0; i < 8; ++i) ov[i] = f2bf(tile[(tg * 8 + i) * 65 + orow]);
    *(ushort8*)(wt + (size_t)(cc * 64 + orow) * R + rc * 64 + tg * 8) = ov;
  }
}

// ---------------------------------------------------------------------------
// 256x256 GEMM, K=1024, deepened K-half ring pipeline (R9, best measured).
// ---------------------------------------------------------------------------
template<int NTILE_N, int EPI>
__global__ __launch_bounds__(512, 2) void gemm256(
    const unsigned short* __restrict__ A, const unsigned short* __restrict__ Bt,
    const float* __restrict__ bias,
    unsigned short* __restrict__ o0, unsigned short* __restrict__ o1,
    unsigned short* __restrict__ o2, float* __restrict__ fout) {
  extern __shared__ __align__(16) char smem[];
  const int K = 1024;
  const int nwg = 128 * NTILE_N;
  const int q = nwg >> 3;
  const int wg = ((int)blockIdx.x & 7) * q + ((int)blockIdx.x >> 3);  // XCD swizzle
  const int tm = wg & 127, tn = wg >> 7;
  const int tid = threadIdx.x;
  const int wid = tid >> 6, lane = tid & 63;
  const int wm = wid >> 2, wn = wid & 3;
  const int lr = lane & 15, lg = lane >> 4;

  const int srow = tid >> 2;
  const int sseg = (tid & 3) ^ ((tid >> 3) & 3);
  const unsigned short* aSrc = A + (size_t)(tm * 256 + srow) * K + sseg * 8;
  const unsigned short* bSrc = Bt + (size_t)(tn * 256 + srow) * K + sseg * 8;
  const unsigned ldsT = (unsigned)tid * 16;

  const unsigned psel = (unsigned)((lg ^ ((lr >> 1) & 3)) * 16);
  const unsigned aBase = (unsigned)(wm * 8192 + lr * 64) + psel;
  const unsigned bBase = (unsigned)(16384 + wn * 4096 + lr * 64) + psel;

  f32x4 acc[8][4];
#pragma unroll
  for (int i = 0; i < 8; ++i)
#pragma unroll
    for (int j = 0; j < 4; ++j) acc[i][j] = zero4();

  bf16x8 rA0[4], rA1[4], rB0[4], rB1[4];

  auto SB = [&]() {
    SCHED0();
    __builtin_amdgcn_s_barrier();
    SCHED0();
  };
  auto stage2 = [&](int coffShorts, unsigned slotB) {
#pragma unroll
    for (int pass = 0; pass < 2; ++pass) {
      gload16(aSrc + (size_t)pass * 128 * K + coffShorts,
              smem + slotB + pass * 8192 + ldsT);
      gload16(bSrc + (size_t)pass * 128 * K + coffShorts,
              smem + slotB + 16384 + pass * 8192 + ldsT);
    }
  };
  auto rdA = [&](bf16x8 (&dst)[4], unsigned slotB, int ih) {
    const char* p = smem + slotB + aBase + ih * 4096;
#pragma unroll
    for (int ii = 0; ii < 4; ++ii)
      dst[ii] = ld_bf8((const unsigned short*)(p + ii * 1024));
  };
  auto rdB = [&](bf16x8 (&dst)[4], unsigned slotB) {
    const char* p = smem + slotB + bBase;
#pragma unroll
    for (int j = 0; j < 4; ++j)
      dst[j] = ld_bf8((const unsigned short*)(p + j * 1024));
  };
  auto cluster = [&](int rb, bf16x8 (&a)[4], bf16x8 (&b)[4]) {
    __builtin_amdgcn_s_setprio(1);
#pragma unroll
    for (int ii = 0; ii < 4; ++ii)
#pragma unroll
      for (int j = 0; j < 4; ++j)
        acc[rb + ii][j] = mfma16(b[j], a[ii], acc[rb + ii][j]);
    __builtin_amdgcn_s_setprio(0);
  };

  // prologue: stage tiles 0 and 1 (16 loads), certify t0
  stage2(0, 0u);
  stage2(32, 32768u);
  stage2(64, 65536u);
  stage2(96, 98304u);
  VMC(12);
  SB();
  rdA(rA0, 0u, 0);
  rdB(rB0, 0u);

  for (int t = 0; t < 16; ++t) {
    const unsigned s0  = (unsigned)((2 * t) & 3) * 32768u;
    const unsigned s1  = (unsigned)((2 * t + 1) & 3) * 32768u;
    const unsigned sn0 = (unsigned)((2 * t + 2) & 3) * 32768u;
    rdA(rA1, s0, 1);
    if (t < 15) { VMC(8); } else { VMC(0); }
    SB();
    cluster(0, rA0, rB0);
    if (t < 14) stage2((t + 2) * 64, s0);
    rdA(rA0, s1, 0);
    rdB(rB1, s1);
    SB();
    cluster(4, rA1, rB0);
    rdA(rA1, s1, 1);
    if (t < 14) { VMC(8); } else if (t == 14) { VMC(4); }
    SB();
    cluster(0, rA0, rB1);
    if (t < 14) stage2((t + 2) * 64 + 32, s1);
    if (t < 15) { rdA(rA0, sn0, 0); rdB(rB0, sn0); }
    SB();
    cluster(4, rA1, rB1);
  }

  const int mBase = tm * 256 + wm * 128;
  const int nBase = tn * 256 + wn * 64;
  if (EPI == 0) {
    const int region = nBase >> 10, nn = nBase & 1023, hh = nn >> 6;
    unsigned short* dst = region == 0 ? o0 : (region == 1 ? o1 : o2);
#pragma unroll
    for (int j = 0; j < 4; ++j) {
      const int d0 = (nn & 63) + j * 16 + lg * 4;
      const float4 bv = *(const float4*)(bias + nBase + j * 16 + lg * 4);
#pragma unroll
      for (int i = 0; i < 8; ++i) {
        const int m = mBase + i * 16 + lr;
        const int bb = m >> 13, tq = m & 8191;
        ushort4v pk;
        pk[0] = f2bf(acc[i][j][0] + bv.x);
        pk[1] = f2bf(acc[i][j][1] + bv.y);
        pk[2] = f2bf(acc[i][j][2] + bv.z);
        pk[3] = f2bf(acc[i][j][3] + bv.w);
        *(ushort4v*)(dst + (((size_t)(bb * 16 + hh)) * T_SEQ + tq) * 64 + d0) = pk;
      }
    }
  } else {
#pragma unroll
    for (int j = 0; j < 4; ++j) {
      const int n0 = nBase + j * 16 + lg * 4;
      const float4 bv = *(const float4*)(bias + n0);
#pragma unroll
      for (int i = 0; i < 8; ++i) {
        const int m = mBase + i * 16 + lr;
        float4 ov;
        ov.x = acc[i][j][0] + bv.x;
        ov.y = acc[i][j][1] + bv.y;
        ov.z = acc[i][j][2] + bv.z;
        ov.w = acc[i][j][3] + bv.w;
        *(float4*)(fout + (size_t)m * 1024 + n0) = ov;
      }
    }
  }
}

// ---------------- transpose v [bh][t][d] -> Vt [bh][d][t] ------------------
__global__ __launch_bounds__(256) void transposeV_k(const unsigned short* __restrict__ v,
                                                    unsigned short* __restrict__ vt) {
  __shared__ float tile[64 * 65];
  int tc = blockIdx.x, bh = blockIdx.y;
  int tid = threadIdx.x;
#pragma unroll
  for (int p = 0; p < 2; ++p) {
    int r = p * 32 + (tid >> 3), cg = tid & 7;
    ushort8 u = *(const ushort8*)(v + ((size_t)bh * T_SEQ + (size_t)tc * 64 + r) * 64 + cg * 8);
#pragma unroll
    for (int i = 0; i < 8; ++i) tile[r * 65 + cg * 8 + i] = bf2f(u[i]);
  }
  __syncthreads();
#pragma unroll
  for (int p = 0; p < 2; ++p) {
    int dd = p * 32 + (tid >> 3), tg = tid & 7;
    ushort8 ov;
#pragma unroll
    for (int i = 0; i < 8; ++i) ov[i] = f2bf(tile[(tg * 8 + i) * 65 + dd]);
    *(ushort8*)(vt + ((size_t)bh * 64 + dd) * T_SEQ + (size_t)tc * 64 + tg * 8) = ov;
  }
}

// ---------------- pool K: k [bh][t][d] -> kpool [bh][2016][d] --------------
__global__ __launch_bounds__(256) void poolK_k(const unsigned short* __restrict__ kin,
                                               unsigned short* __restrict__ kpool) {
  __shared__ float buf[64 * 65];
  int chunk = blockIdx.x, bh = blockIdx.y;
  int tid = threadIdx.x;
  int cg = tid & 7, orow = tid >> 3;
  float s[8];
#pragma unroll
  for (int i = 0; i < 8; ++i) s[i] = 0.f;
  const unsigned short* base =
      kin + ((size_t)bh * T_SEQ + chunk * 256 + orow * 8) * 64 + cg * 8;
#pragma unroll
  for (int rr = 0; rr < 8; ++rr) {
    ushort8 v = *(const ushort8*)(base + (size_t)rr * 64);
#pragma unroll
    for (int i = 0; i < 8; ++i) s[i] += bf2f(v[i]);
  }
  unsigned short* kp = kpool + (size_t)bh * NPOOL * 64;
  {
    ushort8 ov;
#pragma unroll
    for (int i = 0; i < 8; ++i) {
      s[i] *= 0.125f;
      ov[i] = f2bf(s[i]);
      buf[orow * 65 + cg * 8 + i] = s[i];
    }
    *(ushort8*)(kp + ((size_t)(chunk * 32 + orow)) * 64 + cg * 8) = ov;
  }
  __syncthreads();
  int srcR = 0, dstR = 32;
#pragma unroll
  for (int lvl = 2; lvl <= 6; ++lvl) {
    int rows = 32 >> (lvl - 1);
    int off = 2048 - (2048 >> (lvl - 1));
    if (orow < rows) {
      ushort8 ov;
      float tv[8];
#pragma unroll
      for (int i = 0; i < 8; ++i) {
        tv[i] = 0.5f * (buf[(srcR + 2 * orow) * 65 + cg * 8 + i] +
                        buf[(srcR + 2 * orow + 1) * 65 + cg * 8 + i]);
        ov[i] = f2bf(tv[i]);
      }
      *(ushort8*)(kp + ((size_t)(off + chunk * rows + orow)) * 64 + cg * 8) = ov;
#pragma unroll
      for (int i = 0; i < 8; ++i) buf[(dstR + orow) * 65 + cg * 8 + i] = tv[i];
    }
    __syncthreads();
    srcR = dstR;
    dstR += rows;
  }
}

// ---------------- pool V (transposed space): Vt -> Vtpool ------------------
__global__ __launch_bounds__(256) void poolV_k(const unsigned short* __restrict__ vt,
                                               unsigned short* __restrict__ vtpool) {
  __shared__ float buf[1024 + 512 + 256 + 128 + 64];
  int d = blockIdx.x, bh = blockIdx.y;
  int tid = threadIdx.x;
  const unsigned short* src = vt + ((size_t)bh * 64 + d) * T_SEQ;
  unsigned short* dst = vtpool + ((size_t)bh * 64 + d) * NPOOL;
#pragma unroll
  for (int p = 0; p < 4; ++p) {
    int oi = p * 256 + tid;
    ushort8 v = *(const ushort8*)(src + (size_t)oi * 8);
    float s = 0.f;
#pragma unroll
    for (int i = 0; i < 8; ++i) s += bf2f(v[i]);
    s *= 0.125f;
    dst[oi] = f2bf(s);
    buf[oi] = s;
  }
  __syncthreads();
  float* b1 = buf; float* b2 = buf + 1024;
#pragma unroll
  for (int p = 0; p < 2; ++p) {
    int oi = p * 256 + tid;
    float s = 0.5f * (b1[2 * oi] + b1[2 * oi + 1]);
    dst[1024 + oi] = f2bf(s);
    b2[oi] = s;
  }
  __syncthreads();
  float* b3 = b2 + 512;
  {
    float s = 0.5f * (b2[2 * tid] + b2[2 * tid + 1]);
    dst[1536 + tid] = f2bf(s);
    b3[tid] = s;
  }
  __syncthreads();
  float* b4 = b3 + 256;
  if (tid < 128) {
    float s = 0.5f * (b3[2 * tid] + b3[2 * tid + 1]);
    dst[1792 + tid] = f2bf(s);
    b4[tid] = s;
  }
  __syncthreads();
  float* b5 = b4 + 128;
  if (tid < 64) {
    float s = 0.5f * (b4[2 * tid] + b4[2 * tid + 1]);
    dst[1920 + tid] = f2bf(s);
    b5[tid] = s;
  }
  __syncthreads();
  if (tid < 32) {
    float s = 0.5f * (b5[2 * tid] + b5[2 * tid + 1]);
    dst[1984 + tid] = f2bf(s);
  }
}

// ---------------- fused hierarchical attention (swapped QK^T) --------------
// R14 structure: single aliased KV buffer; K DMA'd pre-QK; V DMA'd after the
// post-QK barrier into the same space; per-kc PV fragment assembly.
__global__ __launch_bounds__(256, 4) void attn_k(const unsigned short* __restrict__ q,
                                                 const unsigned short* __restrict__ k,
                                                 const unsigned short* __restrict__ kpool,
                                                 const unsigned short* __restrict__ vt,
                                                 const unsigned short* __restrict__ vtpool,
                                                 unsigned short* __restrict__ o) {
  const int bidx = (int)blockIdx.x;
  const int g = (bidx & 7) * 16 + (bidx >> 3);   // XCD-bucketed fine block
  const int bh = blockIdx.y;
  const int tid = threadIdx.x;
  const int w = tid >> 6, l = tid & 63;
  const int lr = l & 15, lg = l >> 4;
  __shared__ unsigned short KV[224 * 64];   // 28672B: K-window, then V-window

  const size_t qoff = ((size_t)bh * T_SEQ + (size_t)g * 64 + w * 16 + lr) * 64 + lg * 8;
  bf16x8 aq0 = ld_bf8(q + qoff);
  bf16x8 aq1 = ld_bf8(q + qoff + 32);
  SCHED0();

  // ---- K-window staging: 7 passes x 32 rows; dest row*128 + seg*16 ----
  const int krow = tid >> 3;
  const int kseg = tid & 7;
#pragma unroll
  for (int p = 0; p < 7; ++p) {
    const int row = p * 32 + krow;
    const unsigned short* src;
    if (row < 128) {
      int t0 = (g - 1) * 64 + row;
      if (t0 < 0) t0 = 0;
      src = k + ((size_t)bh * T_SEQ + t0) * 64;
    } else {
      const int pr = row - 128;
      const int lvl0 = pr >> 4;
      const int off = 2048 - (2048 >> lvl0);
      const int gl = g >> lvl0;
      int st = (gl - 2) * 8 + (pr & 15);
      if (st < 0) st = 0;
      src = kpool + ((size_t)bh * NPOOL + off + st) * 64;
    }
    gload16(src + (kseg ^ (row & 7)) * 8,
            ((char*)KV) + p * 4096 + (unsigned)tid * 16);
  }
  VMC(0);                          // Q + K drained
  __builtin_amdgcn_s_barrier();    // K staged for all waves
  SCHED0();

  // ---- QK^T from LDS, SWAPPED operands: A=K, B=Q ----
  f32x4 S[14];
#pragma unroll
  for (int ct = 0; ct < 14; ++ct) S[ct] = zero4();
#pragma unroll
  for (int ct = 0; ct < 14; ++ct) {
    const int row = ct * 16 + lr;
    const unsigned short* kr = KV + row * 64;
    const int sw = row & 7;
    S[ct] = mfma16(ld_bf8(kr + (lg ^ sw) * 8), aq0, S[ct]);
    S[ct] = mfma16(ld_bf8(kr + ((lg + 4) ^ sw) * 8), aq1, S[ct]);
  }
  SCHED0();
  __builtin_amdgcn_s_barrier();    // all waves done reading K from KV
  SCHED0();

  // ---- V-window staging into the aliased LDS (DMA lands under softmax) ---
  const int vr = tid >> 2;
  const int vg = tid & 3;
  const int vswz = vg ^ ((vr >> 1) & 3);
#pragma unroll
  for (int s = 0; s < 7; ++s) {
    const int colsh = s * 32 + vswz * 8;
    const unsigned short* src;
    if (colsh < 128) {
      int t0 = (g - 1) * 64 + colsh;
      if (t0 < 0) t0 = 0;
      src = vt + ((size_t)bh * 64 + vr) * T_SEQ + t0;
    } else {
      const int c = colsh - 128;
      const int lvl = c >> 4;
      const int off = 2048 - (2048 >> lvl);
      const int gl = g >> lvl;
      int start = (gl - 2) * 8 + (c & 15);
      if (start < 0) start = 0;
      src = vtpool + ((size_t)bh * 64 + vr) * NPOOL + off + start;
    }
    gload16(src, ((char*)KV) + s * 4096 + (unsigned)tid * 16);
  }
  SCHED0();

  // ---- mask + softmax: lane owns q = w*16+lr; k = ct*16 + lg*4 + e ----
  const float NEGF = -1e30f;
  const int qq = w * 16 + lr;
#pragma unroll
  for (int ct = 0; ct < 14; ++ct) {
#pragma unroll
    for (int e = 0; e < 4; ++e) {
      float s = S[ct][e] * 0.125f;
      bool valid;
      if (ct < 8) {
        int kk = ct * 16 + lg * 4 + e;
        valid = (kk > qq) && (kk <= qq + 64) && ((g >= 1) || (kk >= 64));
      } else {
        int lvl = ct - 7;
        int gl = g >> (lvl - 1);
        valid = gl >= ((lg < 2) ? 2 : 1);
      }
      S[ct][e] = valid ? s : NEGF;
    }
  }
  float mx = S[0][0];
#pragma unroll
  for (int ct = 0; ct < 14; ++ct)
#pragma unroll
    for (int e = 0; e < 4; ++e) mx = fmaxf(mx, S[ct][e]);
  mx = fmaxf(mx, __shfl_xor(mx, 16));
  mx = fmaxf(mx, __shfl_xor(mx, 32));
  float sum = 0.f;
#pragma unroll
  for (int ct = 0; ct < 14; ++ct) {
    const float sc = (ct < 8) ? 1.0f : (float)(8 << (ct - 8));
#pragma unroll
    for (int e = 0; e < 4; ++e) {
      float ev = sc * __expf(S[ct][e] - mx);
      S[ct][e] = ev;
      sum += ev;
    }
  }
  sum += __shfl_xor(sum, 16);
  sum += __shfl_xor(sum, 32);
  const float invd = 1.0f / sum;

  // ---- P -> bf16 words in registers (S dies here) ----
  unsigned pw[14][2];
#pragma unroll
  for (int ct = 0; ct < 14; ++ct) {
    float p0 = S[ct][0] * invd, p1 = S[ct][1] * invd;
    float p2 = S[ct][2] * invd, p3 = S[ct][3] * invd;
    asm("v_cvt_pk_bf16_f32 %0, %1, %2" : "=v"(pw[ct][0]) : "v"(p0), "v"(p1));
    asm("v_cvt_pk_bf16_f32 %0, %1, %2" : "=v"(pw[ct][1]) : "v"(p2), "v"(p3));
  }

  VMC(0);            // V DMA landed (per-wave)
  __syncthreads();   // V visible block-wide

  // ---- PV from LDS; A-fragment assembled per-kc (1 live fragment) ----
  const int src0 = lr + ((lg & 1) << 5);
  const int src1 = src0 + 16;
  const bool odd = (lg & 2) != 0;
  f32x4 O[4];
#pragma unroll
  for (int c2 = 0; c2 < 4; ++c2) O[c2] = zero4();
#pragma unroll
  for (int kc = 0; kc < 7; ++kc) {
    unsigned we0 = __shfl((int)pw[2 * kc][0], src0);
    unsigned we1 = __shfl((int)pw[2 * kc][1], src0);
    unsigned we2 = __shfl((int)pw[2 * kc][0], src1);
    unsigned we3 = __shfl((int)pw[2 * kc][1], src1);
    unsigned wo0 = __shfl((int)pw[2 * kc + 1][0], src0);
    unsigned wo1 = __shfl((int)pw[2 * kc + 1][1], src0);
    unsigned wo2 = __shfl((int)pw[2 * kc + 1][0], src1);
    unsigned wo3 = __shfl((int)pw[2 * kc + 1][1], src1);
    uint4v fw;
    fw[0] = odd ? wo0 : we0;
    fw[1] = odd ? wo1 : we1;
    fw[2] = odd ? wo2 : we2;
    fw[3] = odd ? wo3 : we3;
    bf16x8 paf = __builtin_bit_cast(bf16x8, fw);
#pragma unroll
    for (int c2 = 0; c2 < 4; ++c2) {
      const int row = c2 * 16 + lr;
      bf16x8 vb = ld_bf8(&KV[kc * 2048 + row * 32 + ((lg ^ ((lr >> 1) & 3)) * 8)]);
      O[c2] = mfma16(paf, vb, O[c2]);
    }
  }
  const int bb = bh >> 4, hh = bh & 15;
#pragma unroll
  for (int c2 = 0; c2 < 4; ++c2) {
    int d = c2 * 16 + lr;
#pragma unroll
    for (int e = 0; e < 4; ++e) {
      int t = g * 64 + w * 16 + lg * 4 + e;
      o[((size_t)bb * T_SEQ + t) * 1024 + hh * 64 + d] = f2bf(O[c2][e]);
    }
  }
}

// ---------------------------------------------------------------------------
extern "C" void kernel_launch(void* const* d_in, const int* in_sizes, int n_in,
                              void* d_out, int out_size, void* d_ws, size_t ws_size,
                              hipStream_t stream) {
  const float* x  = (const float*)d_in[0];
  const float* Wa = (const float*)d_in[1];
  const float* ba = (const float*)d_in[2];
  const float* Wp = (const float*)d_in[3];
  const float* bp = (const float*)d_in[4];
  float* out = (float*)d_out;
  char* ws = (char*)d_ws;
  const size_t MB = 1024 * 1024;

  unsigned short* xb  = (unsigned short*)(ws);             // 64MB (dead after GEMM1)
  unsigned short* qb  = (unsigned short*)(ws + 64 * MB);   // 64MB
  unsigned short* kb  = (unsigned short*)(ws + 128 * MB);  // 64MB
  unsigned short* vb  = (unsigned short*)(ws + 192 * MB);  // 64MB (-> attn out)
  unsigned short* vt  = (unsigned short*)(ws + 256 * MB);  // 64MB
  unsigned short* wat = (unsigned short*)(ws + 320 * MB);  // 6MB
  unsigned short* wpt = (unsigned short*)(ws + 326 * MB);  // 2MB
  unsigned short* kpool  = xb;                             // aliases xb
  unsigned short* vtpool = (unsigned short*)(ws + 32 * MB);// aliases xb

  hipFuncSetAttribute((const void*)gemm256<12, 0>,
                      hipFuncAttributeMaxDynamicSharedMemorySize, 131072);
  hipFuncSetAttribute((const void*)gemm256<4, 1>,
                      hipFuncAttributeMaxDynamicSharedMemorySize, 131072);

  castx_k<<<16384, 256, 0, stream>>>(x, xb);
  transposeW_k<<<dim3(48, 16), 256, 0, stream>>>(Wa, wat, 1024, 3072);
  transposeW_k<<<dim3(16, 16), 256, 0, stream>>>(Wp, wpt, 1024, 1024);
  gemm256<12, 0><<<1536, 512, 131072, stream>>>(xb, wat, ba, qb, kb, vb, nullptr);
  transposeV_k<<<dim3(128, 64), 256, 0, stream>>>(vb, vt);
  poolK_k<<<dim3(32, 64), 256, 0, stream>>>(kb, kpool);
  poolV_k<<<dim3(64, 64), 256, 0, stream>>>(vt, vtpool);
  attn_k<<<dim3(128, 64), 256, 0, stream>>>(qb, kb, kpool, vt, vtpool, vb);
  gemm256<4, 1><<<512, 512, 131072, stream>>>(vb, wpt, bp, nullptr, nullptr, nullptr, out);
}